// Round 8
// baseline (2421.267 us; speedup 1.0000x reference)
//
#include <hip/hip_runtime.h>
#include <hip/hip_bf16.h>
#include <cstddef>
#include <cstdint>

#define T_SEQ 512
#define BATCH 256
#define RTOT (BATCH * T_SEQ) /* 131072 rows */
#define CHUNK 32
#define NCHUNK (T_SEQ / CHUNK)

__device__ __forceinline__ float fsigmoid(float x) {
    return 1.0f / (1.0f + __expf(-x));
}
__device__ __forceinline__ float ftanh(float x) {
    // tanh(x) = 1 - 2/(exp(2x)+1); saturates correctly at +-inf
    return 1.0f - 2.0f / (__expf(2.0f * x) + 1.0f);
}

// ---------------------------------------------------------------------------
// Input projection: xp[r, 0:192] = x[r, :] @ W + bi   for both directions.
// (unchanged for attribution)
// ---------------------------------------------------------------------------
template <int DIN, bool EMBED>
__global__ __launch_bounds__(192) void proj_kernel(
    const float* __restrict__ X, const int* __restrict__ tokens,
    const float* __restrict__ emb,
    const float* __restrict__ Wf, const float* __restrict__ bf_,
    const float* __restrict__ Wb, const float* __restrict__ bb_,
    float* __restrict__ xpf, float* __restrict__ xpb)
{
    constexpr int ROWS = 32;
    constexpr int PAD = 36; // row stride 144B: 16B-aligned float4 reads
    __shared__ __align__(16) float xt[DIN][PAD];
    const int r0 = blockIdx.x * ROWS;
    const int tid = threadIdx.x;

    for (int e = tid; e < ROWS * DIN; e += 192) {
        const int row = e / DIN;
        const int i = e % DIN;
        float v;
        if (EMBED) {
            v = emb[(size_t)tokens[r0 + row] * 64 + i];
        } else {
            v = X[(size_t)(r0 + row) * DIN + i];
        }
        xt[i][row] = v;
    }
    __syncthreads();

    const int col = tid; // 0..191
    #pragma unroll
    for (int d = 0; d < 2; d++) {
        const float* __restrict__ W = d ? Wb : Wf;
        const float* __restrict__ bi = d ? bb_ : bf_;
        float* __restrict__ outp = d ? xpb : xpf;
        float acc[ROWS];
        const float b0 = bi[col];
        #pragma unroll
        for (int r = 0; r < ROWS; r++) acc[r] = b0;
        #pragma unroll 4
        for (int i = 0; i < DIN; i++) {
            const float w = W[i * 192 + col]; // coalesced, L1/L2-hot
            #pragma unroll
            for (int r = 0; r < ROWS; r += 4) {
                const float4 x4 = *(const float4*)&xt[i][r];
                acc[r + 0] = fmaf(x4.x, w, acc[r + 0]);
                acc[r + 1] = fmaf(x4.y, w, acc[r + 1]);
                acc[r + 2] = fmaf(x4.z, w, acc[r + 2]);
                acc[r + 3] = fmaf(x4.w, w, acc[r + 3]);
            }
        }
        #pragma unroll
        for (int r = 0; r < ROWS; r++) {
            outp[(size_t)(r0 + r) * 192 + col] = acc[r];
        }
    }
}

// ---------------------------------------------------------------------------
// Recurrent scan v8: 2 CHAINS PER BLOCK (same direction -> SHARED WEIGHTS).
// 256 blocks x 192 threads (3 gate-waves). Wave g owns gate column k=g*64+j.
//
// Why (r0-r7 post-mortem): the scan is serially dependent and the issue
// budget was spent on ONE chain/wave; weights (64/thread) were NEVER kept
// resident by the VGPR allocator (r7: VGPR=88 with stg[8] live -> per-step
// L1 refetch stalls). Here:
//  * 2 chains/block, same dir: one accvgpr_read feeds TWO fmas; the
//    exchange barrier is paid once per step for both chains.
//  * weights parked in AGPRs via "=a" asm (r5 proved residency works;
//    its read tax is now amortized x2).
//  * h in REGISTERS, broadcast via v_readlane (no LDS latency, no lgkmcnt);
//    every wave updates hA,hB redundantly from the shared zr exchange.
//  * ONE lgkmcnt-only barrier/step (no vmcnt drain; xp prefetch + y traffic
//    stay in flight). No __syncthreads in the loop.
//  * y buffered in LDS per 32-step chunk, flushed cooperatively (float4,
//    coalesced) -> zero per-step global stores.
// Gate order matches jnp.split: [0:64]=z, [64:128]=r, [128:192]=h.
// Masked steps (tok==0) carry state.
// ---------------------------------------------------------------------------
__global__ __launch_bounds__(192)
__attribute__((amdgpu_waves_per_eu(1, 1)))
void gru_scan(
    const float* __restrict__ xpf, const float* __restrict__ xpb,
    const float* __restrict__ whf, const float* __restrict__ whb,
    const float* __restrict__ bbf, const float* __restrict__ bbb,
    const int* __restrict__ tokens,
    float* __restrict__ y,        // [RTOT,128] or nullptr
    float* __restrict__ hfinal)   // [BATCH,128] or nullptr
{
    const int blk = blockIdx.x;   // 0..255
    const int dir = blk >> 7;
    const int bp  = blk & 127;
    const int bA = bp * 2, bB = bp * 2 + 1;
    const float* __restrict__ xp  = dir ? xpb : xpf;
    const float* __restrict__ wh  = dir ? whb : whf;
    const float* __restrict__ bbp_ = dir ? bbb : bbf;
    const int k = threadIdx.x;  // 0..191 = gate column
    const int j = k & 63;
    const int g = k >> 6;       // wave: 0=z, 1=r, 2=candidate

    // slots: {zA,zB,rA,rB,rhA,rhB,xhA,xhB}
    __shared__ float zrs[2][8][64];                  // 4 KB
    __shared__ __align__(16) float ybuf[2][CHUNK][64]; // 16 KB
    __shared__ int tokl[2][T_SEQ];                   // 4 KB

    // Park this wave's 64 weight values in AGPRs (shared by both chains).
    float wag[64];
    #pragma unroll
    for (int i = 0; i < 64; i++) {
        const float v = wh[i * 192 + k]; // coalesced (768B/block per i)
        asm volatile("v_accvgpr_write_b32 %0, %1" : "=a"(wag[i]) : "v"(v));
    }
    const float bhk = bbp_[192 + k]; // recurrent bias (bb row 1)

    for (int i = k; i < T_SEQ; i += 192) {
        tokl[0][i] = tokens[(size_t)bA * T_SEQ + i];
        tokl[1][i] = tokens[(size_t)bB * T_SEQ + i];
    }

    const int t0 = dir ? (T_SEQ - 1) : 0;
    const int st = dir ? -1 : 1;
    const size_t baseA = (size_t)bA * T_SEQ, baseB = (size_t)bB * T_SEQ;

    // prefetch depth 2 (registers)
    float xA0 = xp[(baseA + t0) * 192 + k];
    float xB0 = xp[(baseB + t0) * 192 + k];
    float xA1 = xp[(baseA + t0 + st) * 192 + k];
    float xB1 = xp[(baseB + t0 + st) * 192 + k];

    float hA = 0.0f, hB = 0.0f;
    __syncthreads(); // one-time full drain: tokens visible

    int te = t0;
    for (int c = 0; c < NCHUNK; c++) {
        for (int tl = 0; tl < CHUNK; tl++) {
            const int t = c * CHUNK + tl;
            const int p = t & 1;
            // prefetch t+2
            const int tn = (t + 2 < T_SEQ) ? (t + 2) : (T_SEQ - 1);
            const int te2 = t0 + st * tn;
            const float xA2 = xp[(baseA + te2) * 192 + k];
            const float xB2 = xp[(baseB + te2) * 192 + k];

            // rec for own gate, BOTH chains; h broadcast via readlane,
            // weight read once from AGPR feeds two fmas.
            float aA = bhk, aB = bhk;
            const int hAb = __float_as_int(hA), hBb = __float_as_int(hB);
            #pragma unroll
            for (int i = 0; i < 64; i++) {
                float w;
                asm volatile("v_accvgpr_read_b32 %0, %1" : "=v"(w) : "a"(wag[i]));
                const float hiA = __int_as_float(__builtin_amdgcn_readlane(hAb, i));
                const float hiB = __int_as_float(__builtin_amdgcn_readlane(hBb, i));
                aA = fmaf(hiA, w, aA);
                aB = fmaf(hiB, w, aB);
            }

            if (g == 0) {
                zrs[p][0][j] = fsigmoid(xA0 + aA);
                zrs[p][1][j] = fsigmoid(xB0 + aB);
            } else if (g == 1) {
                zrs[p][2][j] = fsigmoid(xA0 + aA);
                zrs[p][3][j] = fsigmoid(xB0 + aB);
            } else {
                zrs[p][4][j] = aA;  zrs[p][5][j] = aB;  // rec_h (bias incl.)
                zrs[p][6][j] = xA0; zrs[p][7][j] = xB0; // x_h
            }
            // LDS-only barrier: vmcnt NOT drained
            asm volatile("s_waitcnt lgkmcnt(0)" ::: "memory");
            __builtin_amdgcn_s_barrier();
            asm volatile("" ::: "memory"); // keep reads below the barrier

            const float zA  = zrs[p][0][j], zB  = zrs[p][1][j];
            const float rA  = zrs[p][2][j], rB  = zrs[p][3][j];
            const float rhA = zrs[p][4][j], rhB = zrs[p][5][j];
            const float xhA = zrs[p][6][j], xhB = zrs[p][7][j];
            const float cA = ftanh(xhA + rA * rhA);
            const float cB = ftanh(xhB + rB * rhB);
            float nA = zA * hA + (1.0f - zA) * cA;
            float nB = zB * hB + (1.0f - zB) * cB;
            if (!(tokl[0][te] > 0)) nA = hA; // Keras mask: carry state
            if (!(tokl[1][te] > 0)) nB = hB;
            hA = nA; hB = nB;
            if (g == 2 && y) {
                ybuf[0][tl][j] = hA;
                ybuf[1][tl][j] = hB;
            }
            te += st;
            xA0 = xA1; xA1 = xA2;
            xB0 = xB1; xB1 = xB2;
        }
        if (y) {
            // flush chunk: make wave2's ybuf writes visible, then coalesced
            // float4 stores by all 192 threads. 2 chains x 32 rows x 16 f4.
            asm volatile("s_waitcnt lgkmcnt(0)" ::: "memory");
            __builtin_amdgcn_s_barrier();
            asm volatile("" ::: "memory");
            for (int idx = k; idx < 2 * CHUNK * 16; idx += 192) {
                const int q   = idx & 15;
                const int row = (idx >> 4) & (CHUNK - 1);
                const int ch  = idx >> 9;
                const int tt  = t0 + st * (c * CHUNK + row);
                const size_t rb = (ch ? baseB : baseA) + tt;
                const float4 v = *(const float4*)&ybuf[ch][row][q * 4];
                *(float4*)&y[rb * 128 + (dir << 6) + q * 4] = v;
            }
            __builtin_amdgcn_s_barrier(); // ybuf reusable next chunk
            asm volatile("" ::: "memory");
        }
    }
    if (hfinal && g == 2) {
        hfinal[bA * 128 + (dir << 6) + j] = hA;
        hfinal[bB * 128 + (dir << 6) + j] = hB;
    }
}

// ---------------------------------------------------------------------------
// MLP head: one block (1 wave) per batch row. (unchanged)
// ---------------------------------------------------------------------------
__global__ __launch_bounds__(64) void mlp_kernel(
    const float* __restrict__ hcat, // [BATCH,128]
    const float* __restrict__ wd1, const float* __restrict__ bd1,
    const float* __restrict__ wd2, const float* __restrict__ bd2,
    const float* __restrict__ wd3, const float* __restrict__ bd3,
    const float* __restrict__ wo, const float* __restrict__ bo,
    float* __restrict__ outp)       // [BATCH,28]
{
    const int b = blockIdx.x;
    const int j = threadIdx.x; // 0..63
    __shared__ float x0[128];
    __shared__ float x1[64];
    x0[j] = hcat[b * 128 + j];
    x0[j + 64] = hcat[b * 128 + 64 + j];
    __syncthreads();
    float a = bd1[j];
    #pragma unroll 4
    for (int i = 0; i < 128; i++) a = fmaf(x0[i], wd1[i * 64 + j], a);
    a = fmaxf(a, 0.0f);
    x1[j] = a;
    __syncthreads();
    float a2 = bd2[j];
    #pragma unroll 4
    for (int i = 0; i < 64; i++) a2 = fmaf(x1[i], wd2[i * 64 + j], a2);
    a2 = fmaxf(a2, 0.0f);
    __syncthreads();
    x1[j] = a2;
    __syncthreads();
    float a3 = bd3[j];
    #pragma unroll 4
    for (int i = 0; i < 64; i++) a3 = fmaf(x1[i], wd3[i * 64 + j], a3);
    a3 = fmaxf(a3, 0.0f);
    __syncthreads();
    x1[j] = a3;
    __syncthreads();
    if (j < 28) {
        float o = bo[j];
        #pragma unroll 4
        for (int i = 0; i < 64; i++) o = fmaf(x1[i], wo[i * 28 + j], o);
        outp[b * 28 + j] = fsigmoid(o);
    }
}

// ---------------------------------------------------------------------------
extern "C" void kernel_launch(void* const* d_in, const int* in_sizes, int n_in,
                              void* d_out, int out_size, void* d_ws, size_t ws_size,
                              hipStream_t stream)
{
    const int* tokens  = (const int*)d_in[0];
    const float* emb   = (const float*)d_in[1];
    const float* wi1f  = (const float*)d_in[2];
    const float* wh1f  = (const float*)d_in[3];
    const float* bb1f  = (const float*)d_in[4];
    const float* wi1b  = (const float*)d_in[5];
    const float* wh1b  = (const float*)d_in[6];
    const float* bb1b  = (const float*)d_in[7];
    const float* wi2f  = (const float*)d_in[8];
    const float* wh2f  = (const float*)d_in[9];
    const float* bb2f  = (const float*)d_in[10];
    const float* wi2b  = (const float*)d_in[11];
    const float* wh2b  = (const float*)d_in[12];
    const float* bb2b  = (const float*)d_in[13];
    const float* wi3f  = (const float*)d_in[14];
    const float* wh3f  = (const float*)d_in[15];
    const float* bb3f  = (const float*)d_in[16];
    const float* wi3b  = (const float*)d_in[17];
    const float* wh3b  = (const float*)d_in[18];
    const float* bb3b  = (const float*)d_in[19];
    const float* wd1   = (const float*)d_in[20];
    const float* bd1   = (const float*)d_in[21];
    const float* wd2   = (const float*)d_in[22];
    const float* bd2   = (const float*)d_in[23];
    const float* wd3   = (const float*)d_in[24];
    const float* bd3   = (const float*)d_in[25];
    const float* wo    = (const float*)d_in[26];
    const float* bo    = (const float*)d_in[27];

    // Workspace layout (all fp32) — total EXACTLY 256 MiB:
    //   y    : RTOT*128  (layer output, reused)        67,108,864 B
    //   xpf  : RTOT*192  (fwd input projection)       100,663,296 B
    //   xpb  : RTOT*192  (bwd input projection)       100,663,296 B
    //   hcat : BATCH*128 — ALIASED onto y's space (y is dead after proj3
    //          reads it; the layer-3 scan writes only hfinal).
    float* y    = (float*)d_ws;
    float* xpf  = y + (size_t)RTOT * 128;
    float* xpb  = xpf + (size_t)RTOT * 192;
    float* hcat = y; // alias: y region is dead by the time hcat is written

    const dim3 pb(192), pg(RTOT / 32);

    // Layer 1 (embedding fused into projection)
    proj_kernel<64, true><<<pg, pb, 0, stream>>>(nullptr, tokens, emb,
                                                 wi1f, bb1f, wi1b, bb1b, xpf, xpb);
    gru_scan<<<256, 192, 0, stream>>>(xpf, xpb, wh1f, wh1b, bb1f, bb1b,
                                      tokens, y, nullptr);
    // Layer 2
    proj_kernel<128, false><<<pg, pb, 0, stream>>>(y, nullptr, nullptr,
                                                   wi2f, bb2f, wi2b, bb2b, xpf, xpb);
    gru_scan<<<256, 192, 0, stream>>>(xpf, xpb, wh2f, wh2b, bb2f, bb2b,
                                      tokens, y, nullptr);
    // Layer 3 (final states only)
    proj_kernel<128, false><<<pg, pb, 0, stream>>>(y, nullptr, nullptr,
                                                   wi3f, bb3f, wi3b, bb3b, xpf, xpb);
    gru_scan<<<256, 192, 0, stream>>>(xpf, xpb, wh3f, wh3b, bb3f, bb3b,
                                      tokens, nullptr, hcat);
    // Head
    mlp_kernel<<<256, 64, 0, stream>>>(hcat, wd1, bd1, wd2, bd2, wd3, bd3,
                                       wo, bo, (float*)d_out);
}